// Round 1
// baseline (648.366 us; speedup 1.0000x reference)
//
#include <hip/hip_runtime.h>

typedef __attribute__((ext_vector_type(8))) __bf16 bf16x8;
typedef __attribute__((ext_vector_type(4))) float f32x4;

#define DEV static __device__ __forceinline__

constexpr int B_ = 4, S_ = 2048, H_ = 8;
// fold 1/sqrt(128) * log2(e) into q/qp so softmax uses exp2 directly
constexpr float SCALE_LOG2E = 0.08838834764831845f * 1.4426950408889634f;

// workspace layout (bytes)
constexpr size_t WS_Q2   = 0;                                  // bf16 [B,H,S,256] (q|qp, pre-scaled)
constexpr size_t WS_K2   = WS_Q2  + (size_t)B_*H_*S_*256*2;    // bf16 [B,H,S,256] (k|kp)
constexpr size_t WS_V    = WS_K2  + (size_t)B_*H_*S_*256*2;    // bf16 [B,H,S,128]
constexpr size_t WS_CTX  = WS_V   + (size_t)B_*H_*S_*128*2;    // bf16 [B,S,1024]
constexpr size_t WS_WBF  = WS_CTX + (size_t)B_*S_*1024*2;      // bf16 5 x [1024,128]
constexpr size_t WS_QLIN = WS_WBF + (size_t)5*1024*128*2;      // bf16 [128,1024]
constexpr size_t WS_WCMB = WS_QLIN + (size_t)128*1024*2;       // bf16 [128,128]
constexpr size_t WS_BCMB = WS_WCMB + (size_t)128*128*2;        // f32  [128]

DEV __bf16 f2b(float f) {
    unsigned u = __builtin_bit_cast(unsigned, f);
    unsigned r = u + 0x7fffu + ((u >> 16) & 1u);   // RNE (no NaNs in this problem)
    unsigned short h = (unsigned short)(r >> 16);
    return __builtin_bit_cast(__bf16, h);
}

DEV float fexp2(float x) {
#if __has_builtin(__builtin_amdgcn_exp2f)
    return __builtin_amdgcn_exp2f(x);
#else
    return exp2f(x);
#endif
}

// ---------------- prep: convert weights to bf16 ----------------
__global__ __launch_bounds__(256) void k_prep(const float* wq, const float* wk,
                                              const float* wv, const float* wqp,
                                              const float* wkp, const float* qlin,
                                              char* ws) {
    __bf16* wbf = (__bf16*)(ws + WS_WBF);
    __bf16* qlb = (__bf16*)(ws + WS_QLIN);
    int i = blockIdx.x * 256 + threadIdx.x;   // 0 .. 786431
    if (i < 5 * 131072) {
        int p = i >> 17;
        int e = i & 131071;
        const float* src = p == 0 ? wq : p == 1 ? wk : p == 2 ? wv : p == 3 ? wqp : wkp;
        wbf[i] = f2b(src[e]);
    } else {
        int e = i - 5 * 131072;
        qlb[e] = f2b(qlin[e]);
    }
}

// ---------------- W_comb = vlin_w @ WV_w ; bias_comb = vlin_w @ WV_b + vlin_b --------
__global__ __launch_bounds__(256) void k_wcomb(const float* vlin_w, const float* wv_w,
                                               const float* wv_b, const float* vlin_b,
                                               char* ws) {
    __bf16* wc = (__bf16*)(ws + WS_WCMB);
    float*  bc = (float*)(ws + WS_BCMB);
    int idx = blockIdx.x * 256 + threadIdx.x;   // 0..16383
    int i = idx >> 7, j = idx & 127;
    float acc = 0.f;
    for (int k = 0; k < 1024; ++k)
        acc += vlin_w[i * 1024 + k] * wv_w[k * 128 + j];
    wc[i * 128 + j] = f2b(acc);
    if (idx < 128) {
        float s = 0.f;
        for (int k = 0; k < 1024; ++k) s += vlin_w[idx * 1024 + k] * wv_b[k];
        bc[idx] = s + vlin_b[idx];
    }
}

// ---------------- projections: 5 x ([8192,128] @ [128,1024]^T) ----------------
__global__ __launch_bounds__(256) void k_proj(const float* Qin, const float* Kin,
                                              const float* Vin, const float* QPin,
                                              const float* KPin,
                                              const float* bq, const float* bk,
                                              const float* bv, const float* bqp,
                                              const float* bkp, char* ws) {
    __shared__ __align__(16) __bf16 As[64 * 128];
    int bx = blockIdx.x;
    int nt4 = bx & 3;
    int mt  = (bx >> 2) & 127;
    int p   = bx >> 9;
    const float* src  = p == 0 ? Qin : p == 1 ? Kin : p == 2 ? Vin : p == 3 ? QPin : KPin;
    const float* bias = p == 0 ? bq  : p == 1 ? bk  : p == 2 ? bv  : p == 3 ? bqp  : bkp;
    const __bf16* wb = (const __bf16*)(ws + WS_WBF) + (size_t)p * 131072;
    __bf16* q2 = (__bf16*)(ws + WS_Q2);
    __bf16* k2 = (__bf16*)(ws + WS_K2);
    __bf16* vb = (__bf16*)(ws + WS_V);

    int t = threadIdx.x;
    int lane = t & 63, w = t >> 6;
    int lr = lane & 15, lg = lane >> 4;
    int m0 = mt * 64;

    // stage A: [64 rows][128 k] f32 -> bf16, XOR-swizzled 16B blocks
    #pragma unroll
    for (int i = 0; i < 4; ++i) {
        int c = i * 256 + t;
        int row = c >> 4, col8 = c & 15;
        const float* g = src + (size_t)(m0 + row) * 128 + col8 * 8;
        f32x4 a0 = *(const f32x4*)g;
        f32x4 a1 = *(const f32x4*)(g + 4);
        bf16x8 v;
        v[0]=f2b(a0[0]); v[1]=f2b(a0[1]); v[2]=f2b(a0[2]); v[3]=f2b(a0[3]);
        v[4]=f2b(a1[0]); v[5]=f2b(a1[1]); v[6]=f2b(a1[2]); v[7]=f2b(a1[3]);
        *(bf16x8*)&As[row * 128 + ((col8 ^ (row & 7)) << 3)] = v;
    }
    __syncthreads();

    f32x4 acc[16];
    #pragma unroll
    for (int i = 0; i < 16; ++i) acc[i] = f32x4{0.f, 0.f, 0.f, 0.f};

    #pragma unroll
    for (int ks = 0; ks < 4; ++ks) {
        int arow = w * 16 + lr;
        int cb = ks * 4 + lg;
        bf16x8 a = *(const bf16x8*)&As[arow * 128 + ((cb ^ (arow & 7)) << 3)];
        #pragma unroll
        for (int tn = 0; tn < 16; ++tn) {
            int n = nt4 * 256 + tn * 16 + lr;
            bf16x8 bfr = *(const bf16x8*)&wb[(size_t)n * 128 + ks * 32 + lg * 8];
            acc[tn] = __builtin_amdgcn_mfma_f32_16x16x32_bf16(a, bfr, acc[tn], 0, 0, 0);
        }
    }

    #pragma unroll
    for (int tn = 0; tn < 16; ++tn) {
        int n = nt4 * 256 + tn * 16 + lr;
        float bias_n = bias[n];
        int h = n >> 7, d = n & 127;
        #pragma unroll
        for (int r = 0; r < 4; ++r) {
            int m = m0 + w * 16 + lg * 4 + r;
            int b = m >> 11, s = m & 2047;
            float val = acc[tn][r] + bias_n;
            size_t base = ((size_t)(b * H_ + h) * S_ + s);
            if (p == 0)      q2[base * 256 + d]       = f2b(val * SCALE_LOG2E);
            else if (p == 3) q2[base * 256 + 128 + d] = f2b(val * SCALE_LOG2E);
            else if (p == 1) k2[base * 256 + d]       = f2b(val);
            else if (p == 4) k2[base * 256 + 128 + d] = f2b(val);
            else             vb[base * 128 + d]       = f2b(val);
        }
    }
}

// ---------------- v_out = V_in @ W_comb^T + bias_comb ----------------
__global__ __launch_bounds__(256) void k_vout(const float* Vin, char* ws, float* out) {
    __shared__ __align__(16) __bf16 As[64 * 128];
    const __bf16* wc = (const __bf16*)(ws + WS_WCMB);
    const float*  bc = (const float*)(ws + WS_BCMB);
    int t = threadIdx.x, lane = t & 63, w = t >> 6;
    int lr = lane & 15, lg = lane >> 4;
    int m0 = blockIdx.x * 64;

    #pragma unroll
    for (int i = 0; i < 4; ++i) {
        int c = i * 256 + t;
        int row = c >> 4, col8 = c & 15;
        const float* g = Vin + (size_t)(m0 + row) * 128 + col8 * 8;
        f32x4 a0 = *(const f32x4*)g;
        f32x4 a1 = *(const f32x4*)(g + 4);
        bf16x8 v;
        v[0]=f2b(a0[0]); v[1]=f2b(a0[1]); v[2]=f2b(a0[2]); v[3]=f2b(a0[3]);
        v[4]=f2b(a1[0]); v[5]=f2b(a1[1]); v[6]=f2b(a1[2]); v[7]=f2b(a1[3]);
        *(bf16x8*)&As[row * 128 + ((col8 ^ (row & 7)) << 3)] = v;
    }
    __syncthreads();

    f32x4 acc[8];
    #pragma unroll
    for (int i = 0; i < 8; ++i) acc[i] = f32x4{0.f, 0.f, 0.f, 0.f};

    #pragma unroll
    for (int ks = 0; ks < 4; ++ks) {
        int arow = w * 16 + lr;
        int cb = ks * 4 + lg;
        bf16x8 a = *(const bf16x8*)&As[arow * 128 + ((cb ^ (arow & 7)) << 3)];
        #pragma unroll
        for (int nt = 0; nt < 8; ++nt) {
            bf16x8 b = *(const bf16x8*)&wc[(size_t)(nt * 16 + lr) * 128 + ks * 32 + lg * 8];
            acc[nt] = __builtin_amdgcn_mfma_f32_16x16x32_bf16(a, b, acc[nt], 0, 0, 0);
        }
    }

    #pragma unroll
    for (int r = 0; r < 4; ++r) {
        int m = m0 + w * 16 + lg * 4 + r;
        #pragma unroll
        for (int nt = 0; nt < 8; ++nt) {
            int n = nt * 16 + lr;
            out[(size_t)1048576 + (size_t)m * 128 + n] = acc[nt][r] + bc[n];
        }
    }
}

// ---------------- flash attention, d'=256 (q|qp)·(k|kp), dv=128 ----------------
__global__ __launch_bounds__(256) void k_attn(char* ws) {
    __shared__ __align__(16) __bf16 Ks[64 * 256];      // swizzled K-tile
    __shared__ __align__(16) __bf16 VT[128 * 72];      // V^T tile [d][key], pad 72
    __shared__ __align__(16) __bf16 Ps[4][16 * 88];    // per-wave P tile, stride 88
    const __bf16* q2 = (const __bf16*)(ws + WS_Q2);
    const __bf16* k2 = (const __bf16*)(ws + WS_K2);
    const __bf16* vb = (const __bf16*)(ws + WS_V);
    __bf16* ctx = (__bf16*)(ws + WS_CTX);

    int bx = blockIdx.x;
    int qt = bx & 31, bh = bx >> 5;
    int t = threadIdx.x, lane = t & 63, w = t >> 6;
    int lr = lane & 15, lg = lane >> 4;

    const size_t base2 = (size_t)bh * S_ * 256;
    const size_t baseV = (size_t)bh * S_ * 128;
    int q0 = qt * 64;

    // hold Q' fragments in registers for whole kernel (rows w*16+lr, pre-scaled)
    bf16x8 qf[8];
    {
        const __bf16* qp = q2 + base2 + (size_t)(q0 + w * 16 + lr) * 256;
        #pragma unroll
        for (int ks = 0; ks < 8; ++ks)
            qf[ks] = *(const bf16x8*)(qp + ks * 32 + lg * 8);
    }

    f32x4 cacc[8];
    #pragma unroll
    for (int i = 0; i < 8; ++i) cacc[i] = f32x4{0.f, 0.f, 0.f, 0.f};
    float mrow[4], lrow[4];
    #pragma unroll
    for (int r = 0; r < 4; ++r) { mrow[r] = -1e30f; lrow[r] = 0.f; }

    for (int kt = 0; kt < 32; ++kt) {
        // stage K-tile [64][256] swizzled
        #pragma unroll
        for (int i = 0; i < 8; ++i) {
            int c = i * 256 + t;
            int row = c >> 5, blk = c & 31;
            bf16x8 v = *(const bf16x8*)(k2 + base2 + (size_t)(kt * 64 + row) * 256 + blk * 8);
            *(bf16x8*)&Ks[row * 256 + ((blk ^ (row & 7)) << 3)] = v;
        }
        // stage V^T tile: lane owns key=lane, d8 = i*4+w
        #pragma unroll
        for (int i = 0; i < 4; ++i) {
            int key = lane, d8 = i * 4 + w;
            bf16x8 v = *(const bf16x8*)(vb + baseV + (size_t)(kt * 64 + key) * 128 + d8 * 8);
            #pragma unroll
            for (int j = 0; j < 8; ++j)
                VT[(d8 * 8 + j) * 72 + key] = v[j];
        }
        __syncthreads();

        // scores: 4 key-tiles x 8 k-steps
        f32x4 sacc[4];
        #pragma unroll
        for (int i = 0; i < 4; ++i) sacc[i] = f32x4{0.f, 0.f, 0.f, 0.f};
        #pragma unroll
        for (int ks = 0; ks < 8; ++ks) {
            #pragma unroll
            for (int ct = 0; ct < 4; ++ct) {
                int key = ct * 16 + lr;
                int cb = ks * 4 + lg;
                bf16x8 b = *(const bf16x8*)&Ks[key * 256 + ((cb ^ (key & 7)) << 3)];
                sacc[ct] = __builtin_amdgcn_mfma_f32_16x16x32_bf16(qf[ks], b, sacc[ct], 0, 0, 0);
            }
        }

        // online softmax (rows live in 16-lane groups; masks 1..8 stay in-group)
        float alpha[4];
        #pragma unroll
        for (int r = 0; r < 4; ++r) {
            float tm = fmaxf(fmaxf(sacc[0][r], sacc[1][r]), fmaxf(sacc[2][r], sacc[3][r]));
            tm = fmaxf(tm, __shfl_xor(tm, 1));
            tm = fmaxf(tm, __shfl_xor(tm, 2));
            tm = fmaxf(tm, __shfl_xor(tm, 4));
            tm = fmaxf(tm, __shfl_xor(tm, 8));
            float mn = fmaxf(mrow[r], tm);
            alpha[r] = fexp2(mrow[r] - mn);
            mrow[r] = mn;
            float ps = 0.f;
            #pragma unroll
            for (int ct = 0; ct < 4; ++ct) {
                float pv = fexp2(sacc[ct][r] - mn);
                sacc[ct][r] = pv;
                ps += pv;
            }
            ps += __shfl_xor(ps, 1);
            ps += __shfl_xor(ps, 2);
            ps += __shfl_xor(ps, 4);
            ps += __shfl_xor(ps, 8);
            lrow[r] = lrow[r] * alpha[r] + ps;
        }
        #pragma unroll
        for (int i = 0; i < 8; ++i)
            #pragma unroll
            for (int r = 0; r < 4; ++r)
                cacc[i][r] *= alpha[r];

        // P -> per-wave LDS (row = lg*4+r, key = ct*16+lr)
        #pragma unroll
        for (int ct = 0; ct < 4; ++ct)
            #pragma unroll
            for (int r = 0; r < 4; ++r)
                Ps[w][(lg * 4 + r) * 88 + ct * 16 + lr] = f2b(sacc[ct][r]);

        // PV: ctx += P[16x64] @ V[64x128]
        #pragma unroll
        for (int kp = 0; kp < 2; ++kp) {
            bf16x8 pa = *(const bf16x8*)&Ps[w][lr * 88 + kp * 32 + lg * 8];
            #pragma unroll
            for (int dt = 0; dt < 8; ++dt) {
                bf16x8 bv = *(const bf16x8*)&VT[(dt * 16 + lr) * 72 + kp * 32 + lg * 8];
                cacc[dt] = __builtin_amdgcn_mfma_f32_16x16x32_bf16(pa, bv, cacc[dt], 0, 0, 0);
            }
        }
        __syncthreads();
    }

    // epilogue: normalize by row-sum, write ctx [B,S,1024] bf16
    int b = bh >> 3, h = bh & 7;
    #pragma unroll
    for (int r = 0; r < 4; ++r) {
        float inv = 1.0f / lrow[r];
        int s = q0 + w * 16 + lg * 4 + r;
        size_t obase = ((size_t)(b * S_ + s)) * 1024 + h * 128;
        #pragma unroll
        for (int dt = 0; dt < 8; ++dt)
            ctx[obase + dt * 16 + lr] = f2b(cacc[dt][r] * inv);
    }
}

// ---------------- out = LN(ctx @ qlin^T + qlin_b + Q) ----------------
__global__ __launch_bounds__(256) void k_out(const float* Qin, const float* qlin_b,
                                             const float* ln_g, const float* ln_b,
                                             char* ws, float* out) {
    __shared__ __align__(16) __bf16 As[64 * 128];
    const __bf16* ctx = (const __bf16*)(ws + WS_CTX);
    const __bf16* qlb = (const __bf16*)(ws + WS_QLIN);
    int t = threadIdx.x, lane = t & 63, w = t >> 6;
    int lr = lane & 15, lg = lane >> 4;
    int m0 = blockIdx.x * 64;

    f32x4 acc[8];
    #pragma unroll
    for (int i = 0; i < 8; ++i) acc[i] = f32x4{0.f, 0.f, 0.f, 0.f};

    for (int kc = 0; kc < 8; ++kc) {
        #pragma unroll
        for (int i = 0; i < 4; ++i) {
            int c = i * 256 + t;
            int row = c >> 4, blk = c & 15;
            bf16x8 v = *(const bf16x8*)(ctx + (size_t)(m0 + row) * 1024 + kc * 128 + blk * 8);
            *(bf16x8*)&As[row * 128 + ((blk ^ (row & 7)) << 3)] = v;
        }
        __syncthreads();
        #pragma unroll
        for (int ks = 0; ks < 4; ++ks) {
            int arow = w * 16 + lr;
            int cb = ks * 4 + lg;
            bf16x8 a = *(const bf16x8*)&As[arow * 128 + ((cb ^ (arow & 7)) << 3)];
            #pragma unroll
            for (int nt = 0; nt < 8; ++nt) {
                bf16x8 b = *(const bf16x8*)&qlb[(size_t)(nt * 16 + lr) * 1024 + kc * 128 + ks * 32 + lg * 8];
                acc[nt] = __builtin_amdgcn_mfma_f32_16x16x32_bf16(a, b, acc[nt], 0, 0, 0);
            }
        }
        __syncthreads();
    }

    // epilogue: +bias +residual, LayerNorm across 128 cols (within wave), f32 out
    #pragma unroll
    for (int r = 0; r < 4; ++r) {
        int m = m0 + w * 16 + lg * 4 + r;
        float x[8];
        float sum = 0.f;
        #pragma unroll
        for (int nt = 0; nt < 8; ++nt) {
            int n = nt * 16 + lr;
            float v = acc[nt][r] + qlin_b[n] + Qin[(size_t)m * 128 + n];
            x[nt] = v;
            sum += v;
        }
        sum += __shfl_xor(sum, 1);
        sum += __shfl_xor(sum, 2);
        sum += __shfl_xor(sum, 4);
        sum += __shfl_xor(sum, 8);
        float mean = sum * (1.f / 128.f);
        float sq = 0.f;
        #pragma unroll
        for (int nt = 0; nt < 8; ++nt) {
            float d = x[nt] - mean;
            sq += d * d;
        }
        sq += __shfl_xor(sq, 1);
        sq += __shfl_xor(sq, 2);
        sq += __shfl_xor(sq, 4);
        sq += __shfl_xor(sq, 8);
        float var = sq * (1.f / 128.f);
        float rstd = rsqrtf(var + 1e-5f);
        #pragma unroll
        for (int nt = 0; nt < 8; ++nt) {
            int n = nt * 16 + lr;
            out[(size_t)m * 128 + n] = (x[nt] - mean) * rstd * ln_g[n] + ln_b[n];
        }
    }
}

extern "C" void kernel_launch(void* const* d_in, const int* in_sizes, int n_in,
                              void* d_out, int out_size, void* d_ws, size_t ws_size,
                              hipStream_t stream) {
    (void)in_sizes; (void)n_in; (void)out_size; (void)ws_size;
    const float* Q    = (const float*)d_in[0];
    const float* K    = (const float*)d_in[1];
    const float* V    = (const float*)d_in[2];
    const float* QP   = (const float*)d_in[3];
    const float* KP   = (const float*)d_in[4];
    const float* WQw  = (const float*)d_in[6];
    const float* WQb  = (const float*)d_in[7];
    const float* WKw  = (const float*)d_in[8];
    const float* WKb  = (const float*)d_in[9];
    const float* WVw  = (const float*)d_in[10];
    const float* WVb  = (const float*)d_in[11];
    const float* WQPw = (const float*)d_in[12];
    const float* WQPb = (const float*)d_in[13];
    const float* WKPw = (const float*)d_in[14];
    const float* WKPb = (const float*)d_in[15];
    const float* qlw  = (const float*)d_in[18];
    const float* qlb  = (const float*)d_in[19];
    const float* vlw  = (const float*)d_in[20];
    const float* vlb  = (const float*)d_in[21];
    const float* lng  = (const float*)d_in[22];
    const float* lnb  = (const float*)d_in[23];
    char* ws = (char*)d_ws;
    float* out = (float*)d_out;

    k_prep<<<3072, 256, 0, stream>>>(WQw, WKw, WVw, WQPw, WKPw, qlw, ws);
    k_wcomb<<<64, 256, 0, stream>>>(vlw, WVw, WVb, vlb, ws);
    k_proj<<<2560, 256, 0, stream>>>(Q, K, V, QP, KP, WQb, WKb, WVb, WQPb, WKPb, ws);
    k_vout<<<128, 256, 0, stream>>>(V, ws, out);
    k_attn<<<1024, 256, 0, stream>>>(ws);
    k_out<<<128, 256, 0, stream>>>(Q, qlb, lng, lnb, ws, out);
}

// Round 2
// 381.161 us; speedup vs baseline: 1.7010x; 1.7010x over previous
//
#include <hip/hip_runtime.h>

typedef __attribute__((ext_vector_type(8))) __bf16 bf16x8;
typedef __attribute__((ext_vector_type(4))) float f32x4;
typedef __attribute__((ext_vector_type(16))) float f32x16;
typedef __attribute__((ext_vector_type(4))) unsigned int u32x4;

#define DEV static __device__ __forceinline__

constexpr int B_ = 4, S_ = 2048, H_ = 8;
// fold 1/sqrt(128) * log2(e) into q/qp so softmax uses exp2 directly
constexpr float SCALE_LOG2E = 0.08838834764831845f * 1.4426950408889634f;

// workspace layout (bytes)
constexpr size_t WS_Q2   = 0;                                  // bf16 [B,H,S,256] (q|qp, pre-scaled)
constexpr size_t WS_K2   = WS_Q2  + (size_t)B_*H_*S_*256*2;    // bf16 [B,H,S,256] (k|kp)
constexpr size_t WS_VT   = WS_K2  + (size_t)B_*H_*S_*256*2;    // bf16 [B,H,128,S] (V transposed)
constexpr size_t WS_CTX  = WS_VT  + (size_t)B_*H_*S_*128*2;    // bf16 [B,S,1024]
constexpr size_t WS_WBF  = WS_CTX + (size_t)B_*S_*1024*2;      // bf16 5 x [1024,128]
constexpr size_t WS_QLIN = WS_WBF + (size_t)5*1024*128*2;      // bf16 [128,1024]
constexpr size_t WS_WCMB = WS_QLIN + (size_t)128*1024*2;       // bf16 [128,128]
constexpr size_t WS_BCMB = WS_WCMB + (size_t)128*128*2;        // f32  [128]

DEV __bf16 f2b(float f) {
    unsigned u = __builtin_bit_cast(unsigned, f);
    unsigned r = u + 0x7fffu + ((u >> 16) & 1u);   // RNE (no NaNs in this problem)
    unsigned short h = (unsigned short)(r >> 16);
    return __builtin_bit_cast(__bf16, h);
}
DEV unsigned short b2u(__bf16 x) { return __builtin_bit_cast(unsigned short, x); }

DEV float fexp2(float x) {
#if __has_builtin(__builtin_amdgcn_exp2f)
    return __builtin_amdgcn_exp2f(x);
#else
    return exp2f(x);
#endif
}

DEV unsigned pk2(float a, float b) {
    unsigned r;
    asm("v_cvt_pk_bf16_f32 %0, %1, %2" : "=v"(r) : "v"(a), "v"(b));
    return r;
}

DEV void gload16(const void* g, void* l) {
    __builtin_amdgcn_global_load_lds(
        (const __attribute__((address_space(1))) unsigned int*)g,
        (__attribute__((address_space(3))) unsigned int*)l, 16, 0, 0);
}

// build P fragment (B-operand, k = hi*8+j) from 8 packed S^T regs
#define PACKP(dst, p0,p1,p2,p3,p4,p5,p6,p7) { \
    unsigned a01 = pk2(p0,p1), a23 = pk2(p2,p3); \
    unsigned x1  = pk2(p4,p5), x2  = pk2(p6,p7); \
    asm("v_permlane32_swap_b32 %0, %1" : "+v"(x1), "+v"(a01)); \
    asm("v_permlane32_swap_b32 %0, %1" : "+v"(x2), "+v"(a23)); \
    u32x4 u_{a01, a23, x1, x2}; \
    dst = __builtin_bit_cast(bf16x8, u_); }

// ---------------- prep: convert weights to bf16 ----------------
__global__ __launch_bounds__(256) void k_prep(const float* wq, const float* wk,
                                              const float* wv, const float* wqp,
                                              const float* wkp, const float* qlin,
                                              char* ws) {
    __bf16* wbf = (__bf16*)(ws + WS_WBF);
    __bf16* qlb = (__bf16*)(ws + WS_QLIN);
    int i = blockIdx.x * 256 + threadIdx.x;   // 0 .. 786431
    if (i < 5 * 131072) {
        int p = i >> 17;
        int e = i & 131071;
        const float* src = p == 0 ? wq : p == 1 ? wk : p == 2 ? wv : p == 3 ? wqp : wkp;
        wbf[i] = f2b(src[e]);
    } else {
        int e = i - 5 * 131072;
        qlb[e] = f2b(qlin[e]);
    }
}

// ---------------- W_comb = vlin_w @ WV_w ; bias_comb = vlin_w @ WV_b + vlin_b --------
__global__ __launch_bounds__(256) void k_wcomb(const float* vlin_w, const float* wv_w,
                                               const float* wv_b, const float* vlin_b,
                                               char* ws) {
    __bf16* wc = (__bf16*)(ws + WS_WCMB);
    float*  bc = (float*)(ws + WS_BCMB);
    int idx = blockIdx.x * 256 + threadIdx.x;   // 0..16383
    int i = idx >> 7, j = idx & 127;
    float acc = 0.f;
    for (int k = 0; k < 1024; ++k)
        acc += vlin_w[i * 1024 + k] * wv_w[k * 128 + j];
    wc[i * 128 + j] = f2b(acc);
    if (idx < 128) {
        float s = 0.f;
        for (int k = 0; k < 1024; ++k) s += vlin_w[idx * 1024 + k] * wv_b[k];
        bc[idx] = s + vlin_b[idx];
    }
}

// ---------------- projections: 5 x ([8192,128] @ [128,1024]^T) ----------------
__global__ __launch_bounds__(256) void k_proj(const float* Qin, const float* Kin,
                                              const float* Vin, const float* QPin,
                                              const float* KPin,
                                              const float* bq, const float* bk,
                                              const float* bv, const float* bqp,
                                              const float* bkp, char* ws) {
    __shared__ __align__(16) __bf16 As[64 * 128];
    int bx = blockIdx.x;
    int nt4 = bx & 3;
    int mt  = (bx >> 2) & 127;
    int p   = bx >> 9;
    const float* src  = p == 0 ? Qin : p == 1 ? Kin : p == 2 ? Vin : p == 3 ? QPin : KPin;
    const float* bias = p == 0 ? bq  : p == 1 ? bk  : p == 2 ? bv  : p == 3 ? bqp  : bkp;
    const __bf16* wb = (const __bf16*)(ws + WS_WBF) + (size_t)p * 131072;
    __bf16* q2  = (__bf16*)(ws + WS_Q2);
    __bf16* k2  = (__bf16*)(ws + WS_K2);
    __bf16* vbT = (__bf16*)(ws + WS_VT);

    int t = threadIdx.x;
    int lane = t & 63, w = t >> 6;
    int lr = lane & 15, lg = lane >> 4;
    int m0 = mt * 64;

    // stage A: [64 rows][128 k] f32 -> bf16, XOR-swizzled 16B blocks
    #pragma unroll
    for (int i = 0; i < 4; ++i) {
        int c = i * 256 + t;
        int row = c >> 4, col8 = c & 15;
        const float* g = src + (size_t)(m0 + row) * 128 + col8 * 8;
        f32x4 a0 = *(const f32x4*)g;
        f32x4 a1 = *(const f32x4*)(g + 4);
        bf16x8 v;
        v[0]=f2b(a0[0]); v[1]=f2b(a0[1]); v[2]=f2b(a0[2]); v[3]=f2b(a0[3]);
        v[4]=f2b(a1[0]); v[5]=f2b(a1[1]); v[6]=f2b(a1[2]); v[7]=f2b(a1[3]);
        *(bf16x8*)&As[row * 128 + ((col8 ^ (row & 7)) << 3)] = v;
    }
    __syncthreads();

    f32x4 acc[16];
    #pragma unroll
    for (int i = 0; i < 16; ++i) acc[i] = f32x4{0.f, 0.f, 0.f, 0.f};

    #pragma unroll
    for (int ks = 0; ks < 4; ++ks) {
        int arow = w * 16 + lr;
        int cb = ks * 4 + lg;
        bf16x8 a = *(const bf16x8*)&As[arow * 128 + ((cb ^ (arow & 7)) << 3)];
        #pragma unroll
        for (int tn = 0; tn < 16; ++tn) {
            int n = nt4 * 256 + tn * 16 + lr;
            bf16x8 bfr = *(const bf16x8*)&wb[(size_t)n * 128 + ks * 32 + lg * 8];
            acc[tn] = __builtin_amdgcn_mfma_f32_16x16x32_bf16(a, bfr, acc[tn], 0, 0, 0);
        }
    }

    #pragma unroll
    for (int tn = 0; tn < 16; ++tn) {
        int n = nt4 * 256 + tn * 16 + lr;
        float bias_n = bias[n];
        int h = n >> 7, d = n & 127;
        if (p == 2) {
            // V: write transposed layout [bh][d][s], 4 consecutive s packed as 8B
            int m = m0 + w * 16 + lg * 4;
            int b = m >> 11, s = m & 2047;
            unsigned lo32 = (unsigned)b2u(f2b(acc[tn][0] + bias_n)) |
                            ((unsigned)b2u(f2b(acc[tn][1] + bias_n)) << 16);
            unsigned hi32 = (unsigned)b2u(f2b(acc[tn][2] + bias_n)) |
                            ((unsigned)b2u(f2b(acc[tn][3] + bias_n)) << 16);
            uint2 u; u.x = lo32; u.y = hi32;
            *(uint2*)&vbT[(((size_t)(b * H_ + h)) * 128 + d) * (size_t)S_ + s] = u;
        } else {
            #pragma unroll
            for (int r = 0; r < 4; ++r) {
                int m = m0 + w * 16 + lg * 4 + r;
                int b = m >> 11, s = m & 2047;
                float val = acc[tn][r] + bias_n;
                size_t base = ((size_t)(b * H_ + h) * S_ + s);
                if (p == 0)      q2[base * 256 + d]       = f2b(val * SCALE_LOG2E);
                else if (p == 3) q2[base * 256 + 128 + d] = f2b(val * SCALE_LOG2E);
                else if (p == 1) k2[base * 256 + d]       = f2b(val);
                else             k2[base * 256 + 128 + d] = f2b(val);
            }
        }
    }
}

// ---------------- v_out = V_in @ W_comb^T + bias_comb ----------------
__global__ __launch_bounds__(256) void k_vout(const float* Vin, char* ws, float* out) {
    __shared__ __align__(16) __bf16 As[64 * 128];
    const __bf16* wc = (const __bf16*)(ws + WS_WCMB);
    const float*  bc = (const float*)(ws + WS_BCMB);
    int t = threadIdx.x, lane = t & 63, w = t >> 6;
    int lr = lane & 15, lg = lane >> 4;
    int m0 = blockIdx.x * 64;

    #pragma unroll
    for (int i = 0; i < 4; ++i) {
        int c = i * 256 + t;
        int row = c >> 4, col8 = c & 15;
        const float* g = Vin + (size_t)(m0 + row) * 128 + col8 * 8;
        f32x4 a0 = *(const f32x4*)g;
        f32x4 a1 = *(const f32x4*)(g + 4);
        bf16x8 v;
        v[0]=f2b(a0[0]); v[1]=f2b(a0[1]); v[2]=f2b(a0[2]); v[3]=f2b(a0[3]);
        v[4]=f2b(a1[0]); v[5]=f2b(a1[1]); v[6]=f2b(a1[2]); v[7]=f2b(a1[3]);
        *(bf16x8*)&As[row * 128 + ((col8 ^ (row & 7)) << 3)] = v;
    }
    __syncthreads();

    f32x4 acc[8];
    #pragma unroll
    for (int i = 0; i < 8; ++i) acc[i] = f32x4{0.f, 0.f, 0.f, 0.f};

    #pragma unroll
    for (int ks = 0; ks < 4; ++ks) {
        int arow = w * 16 + lr;
        int cb = ks * 4 + lg;
        bf16x8 a = *(const bf16x8*)&As[arow * 128 + ((cb ^ (arow & 7)) << 3)];
        #pragma unroll
        for (int nt = 0; nt < 8; ++nt) {
            bf16x8 b = *(const bf16x8*)&wc[(size_t)(nt * 16 + lr) * 128 + ks * 32 + lg * 8];
            acc[nt] = __builtin_amdgcn_mfma_f32_16x16x32_bf16(a, b, acc[nt], 0, 0, 0);
        }
    }

    #pragma unroll
    for (int r = 0; r < 4; ++r) {
        int m = m0 + w * 16 + lg * 4 + r;
        #pragma unroll
        for (int nt = 0; nt < 8; ++nt) {
            int n = nt * 16 + lr;
            out[(size_t)1048576 + (size_t)m * 128 + n] = acc[nt][r] + bc[n];
        }
    }
}

// ---------------- flash attention v2: 32x32 MFMA, swapped operands ----------------
// S^T = mfma(K,Q): lane holds q = lane&31, keys in regs (crow).
// ctx^T = mfma(V^T, P): accumulator col = q = lane&31 -> scalar rescale.
__global__ __launch_bounds__(256, 2) void k_attn(char* ws) {
    __shared__ __align__(16) __bf16 Ks[2][64 * 256];   // double-buffered K, src-preswizzled
    __shared__ __align__(16) __bf16 VTs[128 * 64];     // V^T tile, swizzled
    const __bf16* q2 = (const __bf16*)(ws + WS_Q2);
    const __bf16* k2 = (const __bf16*)(ws + WS_K2);
    const __bf16* vT = (const __bf16*)(ws + WS_VT);
    __bf16* ctxg = (__bf16*)(ws + WS_CTX);

    int bx = blockIdx.x;
    int idx = bx >> 3;
    int bh = (bx & 7) * 4 + (idx >> 4);   // XCD-chunked: 4 heads per XCD
    int qt = idx & 15;
    int t = threadIdx.x, lane = t & 63, w = t >> 6;
    int lo = lane & 31, hi = lane >> 5;

    const __bf16* k2b = k2 + (size_t)bh * S_ * 256;
    const __bf16* vTb = vT + (size_t)bh * 128 * S_;
    int q0 = qt * 128;
    int qrow = q0 + w * 32 + lo;

    // Q fragments (B-operand): qf[ks][j] = Q[qrow][ks*16 + hi*8 + j]
    bf16x8 qf[16];
    {
        const __bf16* qp = q2 + ((size_t)bh * S_ + qrow) * 256 + hi * 8;
        #pragma unroll
        for (int ks = 0; ks < 16; ++ks) qf[ks] = *(const bf16x8*)(qp + ks * 16);
    }

    f32x16 ctx[4];
    #pragma unroll
    for (int i = 0; i < 4; ++i)
        #pragma unroll
        for (int j = 0; j < 16; ++j) ctx[i][j] = 0.f;
    float m_r = -1e30f, l_r = 0.f;

    // ---- staging helpers ----
    // K: global_load_lds, source pre-swizzled so LDS stays linear-dest
    int kxm;  // per-call row parity handled inline
    (void)kxm;
    bf16x8 vreg[4];

    // prologue: tile 0
    {
        #pragma unroll
        for (int i = 0; i < 8; ++i) {
            int r0 = w * 16 + i * 2;
            int row = r0 + hi;
            const __bf16* src = k2b + (size_t)row * 256 + (((lane & 31) ^ (row & 7)) << 3);
            gload16(src, &Ks[0][r0 * 256]);
        }
        #pragma unroll
        for (int i = 0; i < 4; ++i) {
            int d = i * 32 + (t >> 3), kb = t & 7;
            vreg[i] = *(const bf16x8*)(vTb + (size_t)d * S_ + kb * 8);
        }
        #pragma unroll
        for (int i = 0; i < 4; ++i) {
            int d = i * 32 + (t >> 3), kb = t & 7;
            *(bf16x8*)&VTs[d * 64 + ((kb ^ (d & 7)) << 3)] = vreg[i];
        }
    }
    __syncthreads();

    int cur = 0;
    for (int kt = 0; kt < 32; ++kt) {
        bool pre = (kt + 1 < 32);
        if (pre) {
            // async K prefetch into other buffer
            #pragma unroll
            for (int i = 0; i < 8; ++i) {
                int r0 = w * 16 + i * 2;
                int row = r0 + hi;
                const __bf16* src = k2b + (size_t)((kt + 1) * 64 + row) * 256 +
                                    (((lane & 31) ^ (row & 7)) << 3);
                gload16(src, &Ks[cur ^ 1][r0 * 256]);
            }
            // V prefetch into regs
            #pragma unroll
            for (int i = 0; i < 4; ++i) {
                int d = i * 32 + (t >> 3), kb = t & 7;
                vreg[i] = *(const bf16x8*)(vTb + (size_t)d * S_ + (kt + 1) * 64 + kb * 8);
            }
        }

        // ---- QK^T (swapped): s0 = keys 0..31, s1 = keys 32..63 ----
        f32x16 s0, s1;
        #pragma unroll
        for (int j = 0; j < 16; ++j) { s0[j] = 0.f; s1[j] = 0.f; }
        int xm = lo & 7;
        #pragma unroll
        for (int ks = 0; ks < 16; ++ks) {
            bf16x8 a0 = *(const bf16x8*)&Ks[cur][lo * 256 + (((2 * ks + hi) ^ xm) << 3)];
            bf16x8 a1 = *(const bf16x8*)&Ks[cur][(32 + lo) * 256 + (((2 * ks + hi) ^ xm) << 3)];
            s0 = __builtin_amdgcn_mfma_f32_32x32x16_bf16(a0, qf[ks], s0, 0, 0, 0);
            s1 = __builtin_amdgcn_mfma_f32_32x32x16_bf16(a1, qf[ks], s1, 0, 0, 0);
        }

        // ---- online softmax (values already in log2 units) ----
        float pm = -1e30f;
        #pragma unroll
        for (int j = 0; j < 16; ++j) pm = fmaxf(pm, fmaxf(s0[j], s1[j]));
        pm = fmaxf(pm, __shfl_xor(pm, 32));
        float mn = fmaxf(m_r, pm);
        float alpha = fexp2(m_r - mn);
        m_r = mn;
        float psum = 0.f;
        #pragma unroll
        for (int j = 0; j < 16; ++j) {
            s0[j] = fexp2(s0[j] - mn); psum += s0[j];
            s1[j] = fexp2(s1[j] - mn); psum += s1[j];
        }
        psum += __shfl_xor(psum, 32);
        l_r = l_r * alpha + psum;
        #pragma unroll
        for (int i = 0; i < 4; ++i)
            #pragma unroll
            for (int j = 0; j < 16; ++j) ctx[i][j] *= alpha;

        // ---- pack P into B-fragments (cvt_pk + permlane32_swap) ----
        bf16x8 pf[4];
        PACKP(pf[0], s0[0], s0[1], s0[2], s0[3], s0[4], s0[5], s0[6], s0[7]);
        PACKP(pf[1], s0[8], s0[9], s0[10], s0[11], s0[12], s0[13], s0[14], s0[15]);
        PACKP(pf[2], s1[0], s1[1], s1[2], s1[3], s1[4], s1[5], s1[6], s1[7]);
        PACKP(pf[3], s1[8], s1[9], s1[10], s1[11], s1[12], s1[13], s1[14], s1[15]);

        // ---- PV (swapped): ctx^T[d][q] += V^T x P ----
        #pragma unroll
        for (int kp = 0; kp < 4; ++kp) {
            #pragma unroll
            for (int ds = 0; ds < 4; ++ds) {
                int row = ds * 32 + lo;
                bf16x8 va = *(const bf16x8*)&VTs[row * 64 + (((2 * kp + hi) ^ xm) << 3)];
                ctx[ds] = __builtin_amdgcn_mfma_f32_32x32x16_bf16(va, pf[kp], ctx[ds], 0, 0, 0);
            }
        }

        __syncthreads();   // everyone done reading Ks[cur]/VTs; drains K-dma for cur^1
        if (pre) {
            #pragma unroll
            for (int i = 0; i < 4; ++i) {
                int d = i * 32 + (t >> 3), kb = t & 7;
                *(bf16x8*)&VTs[d * 64 + ((kb ^ (d & 7)) << 3)] = vreg[i];
            }
        }
        __syncthreads();
        cur ^= 1;
    }

    // ---- epilogue: /l, transpose via LDS bounce, coalesced bf16 write ----
    __syncthreads();
    __bf16* sc = &Ks[0][0] + w * 4096;   // per-wave 32q x 128d region (8KB)
    float inv = 1.f / l_r;
    #pragma unroll
    for (int ds = 0; ds < 4; ++ds) {
        #pragma unroll
        for (int g = 0; g < 4; ++g) {
            #pragma unroll
            for (int h2 = 0; h2 < 2; ++h2) {
                int r = g * 4 + h2 * 2;
                unsigned pv = pk2(ctx[ds][r] * inv, ctx[ds][r + 1] * inv);
                int d = ds * 32 + (r & 3) + 8 * (r >> 2) + 4 * hi;
                *(unsigned*)&sc[lo * 128 + (((d >> 3) ^ (lo & 7)) << 3) + (d & 7)] = pv;
            }
        }
    }
    __syncthreads();
    {
        int b = bh >> 3, h = bh & 7;
        int qq = lane >> 1, half = lane & 1;
        int srow = q0 + w * 32 + qq;
        #pragma unroll
        for (int j = 0; j < 8; ++j) {
            int d8 = half * 8 + j;
            bf16x8 vv = *(const bf16x8*)&sc[qq * 128 + ((d8 ^ (qq & 7)) << 3)];
            *(bf16x8*)&ctxg[((size_t)(b * S_ + srow)) * 1024 + h * 128 + d8 * 8] = vv;
        }
    }
}

// ---------------- out = LN(ctx @ qlin^T + qlin_b + Q) ----------------
__global__ __launch_bounds__(256) void k_out(const float* Qin, const float* qlin_b,
                                             const float* ln_g, const float* ln_b,
                                             char* ws, float* out) {
    __shared__ __align__(16) __bf16 As[64 * 128];
    const __bf16* ctx = (const __bf16*)(ws + WS_CTX);
    const __bf16* qlb = (const __bf16*)(ws + WS_QLIN);
    int t = threadIdx.x, lane = t & 63, w = t >> 6;
    int lr = lane & 15, lg = lane >> 4;
    int m0 = blockIdx.x * 64;

    f32x4 acc[8];
    #pragma unroll
    for (int i = 0; i < 8; ++i) acc[i] = f32x4{0.f, 0.f, 0.f, 0.f};

    for (int kc = 0; kc < 8; ++kc) {
        #pragma unroll
        for (int i = 0; i < 4; ++i) {
            int c = i * 256 + t;
            int row = c >> 4, blk = c & 15;
            bf16x8 v = *(const bf16x8*)(ctx + (size_t)(m0 + row) * 1024 + kc * 128 + blk * 8);
            *(bf16x8*)&As[row * 128 + ((blk ^ (row & 7)) << 3)] = v;
        }
        __syncthreads();
        #pragma unroll
        for (int ks = 0; ks < 4; ++ks) {
            int arow = w * 16 + lr;
            int cb = ks * 4 + lg;
            bf16x8 a = *(const bf16x8*)&As[arow * 128 + ((cb ^ (arow & 7)) << 3)];
            #pragma unroll
            for (int nt = 0; nt < 8; ++nt) {
                bf16x8 b = *(const bf16x8*)&qlb[(size_t)(nt * 16 + lr) * 1024 + kc * 128 + ks * 32 + lg * 8];
                acc[nt] = __builtin_amdgcn_mfma_f32_16x16x32_bf16(a, b, acc[nt], 0, 0, 0);
            }
        }
        __syncthreads();
    }

    #pragma unroll
    for (int r = 0; r < 4; ++r) {
        int m = m0 + w * 16 + lg * 4 + r;
        float x[8];
        float sum = 0.f;
        #pragma unroll
        for (int nt = 0; nt < 8; ++nt) {
            int n = nt * 16 + lr;
            float v = acc[nt][r] + qlin_b[n] + Qin[(size_t)m * 128 + n];
            x[nt] = v;
            sum += v;
        }
        sum += __shfl_xor(sum, 1);
        sum += __shfl_xor(sum, 2);
        sum += __shfl_xor(sum, 4);
        sum += __shfl_xor(sum, 8);
        float mean = sum * (1.f / 128.f);
        float sq = 0.f;
        #pragma unroll
        for (int nt = 0; nt < 8; ++nt) {
            float d = x[nt] - mean;
            sq += d * d;
        }
        sq += __shfl_xor(sq, 1);
        sq += __shfl_xor(sq, 2);
        sq += __shfl_xor(sq, 4);
        sq += __shfl_xor(sq, 8);
        float var = sq * (1.f / 128.f);
        float rstd = rsqrtf(var + 1e-5f);
        #pragma unroll
        for (int nt = 0; nt < 8; ++nt) {
            int n = nt * 16 + lr;
            out[(size_t)m * 128 + n] = (x[nt] - mean) * rstd * ln_g[n] + ln_b[n];
        }
    }
}

extern "C" void kernel_launch(void* const* d_in, const int* in_sizes, int n_in,
                              void* d_out, int out_size, void* d_ws, size_t ws_size,
                              hipStream_t stream) {
    (void)in_sizes; (void)n_in; (void)out_size; (void)ws_size;
    const float* Q    = (const float*)d_in[0];
    const float* K    = (const float*)d_in[1];
    const float* V    = (const float*)d_in[2];
    const float* QP   = (const float*)d_in[3];
    const float* KP   = (const float*)d_in[4];
    const float* WQw  = (const float*)d_in[6];
    const float* WQb  = (const float*)d_in[7];
    const float* WKw  = (const float*)d_in[8];
    const float* WKb  = (const float*)d_in[9];
    const float* WVw  = (const float*)d_in[10];
    const float* WVb  = (const float*)d_in[11];
    const float* WQPw = (const float*)d_in[12];
    const float* WQPb = (const float*)d_in[13];
    const float* WKPw = (const float*)d_in[14];
    const float* WKPb = (const float*)d_in[15];
    const float* qlw  = (const float*)d_in[18];
    const float* qlb  = (const float*)d_in[19];
    const float* vlw  = (const float*)d_in[20];
    const float* vlb  = (const float*)d_in[21];
    const float* lng  = (const float*)d_in[22];
    const float* lnb  = (const float*)d_in[23];
    char* ws = (char*)d_ws;
    float* out = (float*)d_out;

    k_prep<<<3072, 256, 0, stream>>>(WQw, WKw, WVw, WQPw, WKPw, qlw, ws);
    k_wcomb<<<64, 256, 0, stream>>>(vlw, WVw, WVb, vlb, ws);
    k_proj<<<2560, 256, 0, stream>>>(Q, K, V, QP, KP, WQb, WKb, WVb, WQPb, WKPb, ws);
    k_vout<<<128, 256, 0, stream>>>(V, ws, out);
    k_attn<<<512, 256, 0, stream>>>(ws);
    k_out<<<128, 256, 0, stream>>>(Q, qlb, lng, lnb, ws, out);
}

// Round 3
// 257.216 us; speedup vs baseline: 2.5207x; 1.4819x over previous
//
#include <hip/hip_runtime.h>

typedef __attribute__((ext_vector_type(8))) __bf16 bf16x8;
typedef __attribute__((ext_vector_type(4))) float f32x4;
typedef __attribute__((ext_vector_type(16))) float f32x16;
typedef __attribute__((ext_vector_type(4))) unsigned int u32x4;

#define DEV static __device__ __forceinline__

constexpr int B_ = 4, S_ = 2048, H_ = 8;
// fold 1/sqrt(128) * log2(e) into q/qp so softmax uses exp2 directly
constexpr float SCALE_LOG2E = 0.08838834764831845f * 1.4426950408889634f;

// workspace layout (bytes)
constexpr size_t WS_Q2   = 0;                                  // bf16 [B,H,S,256] (q|qp, pre-scaled)
constexpr size_t WS_K2   = WS_Q2  + (size_t)B_*H_*S_*256*2;    // bf16 [B,H,S,256] (k|kp)
constexpr size_t WS_VT   = WS_K2  + (size_t)B_*H_*S_*256*2;    // bf16 [B,H,128,S] (V transposed)
constexpr size_t WS_CTX  = WS_VT  + (size_t)B_*H_*S_*128*2;    // bf16 [B,S,1024]
constexpr size_t WS_WBF  = WS_CTX + (size_t)B_*S_*1024*2;      // bf16 5 x [1024,128]
constexpr size_t WS_QLIN = WS_WBF + (size_t)5*1024*128*2;      // bf16 [128,1024]
constexpr size_t WS_WCMB = WS_QLIN + (size_t)128*1024*2;       // bf16 [128,128]
constexpr size_t WS_BCMB = WS_WCMB + (size_t)128*128*2;        // f32  [128]

DEV __bf16 f2b(float f) {
    unsigned u = __builtin_bit_cast(unsigned, f);
    unsigned r = u + 0x7fffu + ((u >> 16) & 1u);   // RNE (no NaNs in this problem)
    unsigned short h = (unsigned short)(r >> 16);
    return __builtin_bit_cast(__bf16, h);
}

DEV float fexp2(float x) {
#if __has_builtin(__builtin_amdgcn_exp2f)
    return __builtin_amdgcn_exp2f(x);
#else
    return exp2f(x);
#endif
}

DEV unsigned pk2(float a, float b) {
    unsigned r;
    asm("v_cvt_pk_bf16_f32 %0, %1, %2" : "=v"(r) : "v"(a), "v"(b));
    return r;
}

DEV bf16x8 cvt8(f32x4 a, f32x4 b) {
    u32x4 u{pk2(a[0], a[1]), pk2(a[2], a[3]), pk2(b[0], b[1]), pk2(b[2], b[3])};
    return __builtin_bit_cast(bf16x8, u);
}

DEV void gload16(const void* g, void* l) {
    __builtin_amdgcn_global_load_lds(
        (const __attribute__((address_space(1))) unsigned int*)g,
        (__attribute__((address_space(3))) unsigned int*)l, 16, 0, 0);
}

// build P fragment (B-operand, k = hi*8+j) from 8 packed S^T regs
#define PACKP(dst, p0,p1,p2,p3,p4,p5,p6,p7) { \
    unsigned a01 = pk2(p0,p1), a23 = pk2(p2,p3); \
    unsigned x1  = pk2(p4,p5), x2  = pk2(p6,p7); \
    asm("v_permlane32_swap_b32 %0, %1" : "+v"(x1), "+v"(a01)); \
    asm("v_permlane32_swap_b32 %0, %1" : "+v"(x2), "+v"(a23)); \
    u32x4 u_{a01, a23, x1, x2}; \
    dst = __builtin_bit_cast(bf16x8, u_); }

// ---------------- prep: weights->bf16 (bx<384) + W_comb MFMA (bx>=384) -------------
__global__ __launch_bounds__(256) void k_prep(const float* wq, const float* wk,
                                              const float* wv, const float* wqp,
                                              const float* wkp, const float* qlin,
                                              const float* vlin_w, const float* wv_b,
                                              const float* vlin_b, char* ws) {
    int bx = blockIdx.x, t = threadIdx.x;
    if (bx < 384) {
        __bf16* wbf = (__bf16*)(ws + WS_WBF);
        __bf16* qlb = (__bf16*)(ws + WS_QLIN);
        size_t i8 = ((size_t)bx * 256 + t) * 8;
        if (i8 < 655360) {
            int p = (int)(i8 >> 17);
            size_t e = i8 & 131071;
            const float* src = p == 0 ? wq : p == 1 ? wk : p == 2 ? wv : p == 3 ? wqp : wkp;
            f32x4 a = *(const f32x4*)(src + e);
            f32x4 b = *(const f32x4*)(src + e + 4);
            *(bf16x8*)(wbf + i8) = cvt8(a, b);
        } else {
            size_t e = i8 - 655360;
            f32x4 a = *(const f32x4*)(qlin + e);
            f32x4 b = *(const f32x4*)(qlin + e + 4);
            *(bf16x8*)(qlb + e) = cvt8(a, b);
        }
    } else {
        // W_comb = vlin_w @ wv  (M=128 rows of vlin, N=128 cols of wv), K=1024
        __bf16* wc = (__bf16*)(ws + WS_WCMB);
        float*  bc = (float*)(ws + WS_BCMB);
        int mb = bx - 384;                       // 0..3 -> 32 rows each
        int m0 = mb * 32;
        int lane = t & 63, w = t >> 6, lo = lane & 31, hi = lane >> 5;
        int j = w * 32 + lo;                     // output col (wave-split over N)
        f32x16 acc;
        #pragma unroll
        for (int i = 0; i < 16; ++i) acc[i] = 0.f;
        const float* arow = vlin_w + (size_t)(m0 + lo) * 1024;
        #pragma unroll 4
        for (int ks = 0; ks < 64; ++ks) {
            int kb = ks * 16 + hi * 8;
            f32x4 a0 = *(const f32x4*)(arow + kb);
            f32x4 a1 = *(const f32x4*)(arow + kb + 4);
            bf16x8 af = cvt8(a0, a1);
            const float* wp = wv + (size_t)kb * 128 + j;
            float b0 = wp[0], b1 = wp[128], b2 = wp[256], b3 = wp[384];
            float b4 = wp[512], b5 = wp[640], b6 = wp[768], b7 = wp[896];
            u32x4 u{pk2(b0, b1), pk2(b2, b3), pk2(b4, b5), pk2(b6, b7)};
            bf16x8 bf = __builtin_bit_cast(bf16x8, u);
            acc = __builtin_amdgcn_mfma_f32_32x32x16_bf16(af, bf, acc, 0, 0, 0);
        }
        __bf16* wp2 = wc + (size_t)(m0 + 4 * hi) * 128 + j;
        #pragma unroll
        for (int r = 0; r < 16; ++r)
            wp2[((r & 3) + 8 * (r >> 2)) * 128] = f2b(acc[r]);
        // bias_comb
        int i = m0 + (t >> 3), part = t & 7;
        float s = 0.f;
        const float* vr = vlin_w + (size_t)i * 1024 + part * 128;
        const float* br = wv_b + part * 128;
        #pragma unroll 8
        for (int kk = 0; kk < 32; ++kk) {
            f32x4 a = *(const f32x4*)(vr + kk * 4);
            f32x4 b = *(const f32x4*)(br + kk * 4);
            s += a[0]*b[0] + a[1]*b[1] + a[2]*b[2] + a[3]*b[3];
        }
        s += __shfl_xor(s, 1);
        s += __shfl_xor(s, 2);
        s += __shfl_xor(s, 4);
        if (part == 0) bc[i] = s + vlin_b[i];
    }
}

// ---------------- projections (LDS-free direct MFMA) + v_out ----------------
__global__ __launch_bounds__(256) void k_proj(const float* Qin, const float* Kin,
                                              const float* Vin, const float* QPin,
                                              const float* KPin,
                                              const float* bq, const float* bk,
                                              const float* bv, const float* bqp,
                                              const float* bkp, char* ws, float* out) {
    int bx = blockIdx.x, t = threadIdx.x;
    int lane = t & 63, w = t >> 6, lo = lane & 31, hi = lane >> 5;
    __bf16* q2  = (__bf16*)(ws + WS_Q2);
    __bf16* k2  = (__bf16*)(ws + WS_K2);
    __bf16* vbT = (__bf16*)(ws + WS_VT);
    if (bx < 2560) {
        int p = bx >> 9, r5 = bx & 511, mt = r5 >> 3, nq = r5 & 7;
        int m0 = mt * 128 + w * 32, n0 = nq * 128;
        const float* src  = p == 0 ? Qin : p == 1 ? Kin : p == 2 ? Vin : p == 3 ? QPin : KPin;
        const float* bias = p == 0 ? bq  : p == 1 ? bk  : p == 2 ? bv  : p == 3 ? bqp  : bkp;
        const __bf16* wb = (const __bf16*)(ws + WS_WBF) + (size_t)p * 131072;
        f32x16 acc[4];
        #pragma unroll
        for (int g = 0; g < 4; ++g)
            #pragma unroll
            for (int i = 0; i < 16; ++i) acc[g][i] = 0.f;
        const float* arow = src + (size_t)(m0 + lo) * 128;
        #pragma unroll
        for (int ks = 0; ks < 8; ++ks) {
            int kb = ks * 16 + hi * 8;
            f32x4 a0 = *(const f32x4*)(arow + kb);
            f32x4 a1 = *(const f32x4*)(arow + kb + 4);
            bf16x8 af = cvt8(a0, a1);
            #pragma unroll
            for (int g = 0; g < 4; ++g) {
                bf16x8 bf = *(const bf16x8*)&wb[(size_t)(n0 + g * 32 + lo) * 128 + kb];
                acc[g] = __builtin_amdgcn_mfma_f32_32x32x16_bf16(af, bf, acc[g], 0, 0, 0);
            }
        }
        int b = m0 >> 11, s0 = m0 & 2047;     // wave-uniform (m0 mult of 32)
        if (p == 2) {
            #pragma unroll
            for (int g = 0; g < 4; ++g) {
                int n = n0 + g * 32 + lo, h = n >> 7, d = n & 127;
                float bn = bias[n];
                __bf16* dp = vbT + (((size_t)(b * H_ + h)) * 128 + d) * (size_t)S_ + s0 + 4 * hi;
                #pragma unroll
                for (int rq = 0; rq < 4; ++rq) {
                    unsigned w0 = pk2(acc[g][rq*4+0] + bn, acc[g][rq*4+1] + bn);
                    unsigned w1 = pk2(acc[g][rq*4+2] + bn, acc[g][rq*4+3] + bn);
                    uint2 u; u.x = w0; u.y = w1;
                    *(uint2*)&dp[rq * 8] = u;
                }
            }
        } else {
            float sc = (p == 0 || p == 3) ? SCALE_LOG2E : 1.f;
            int off = (p == 0 || p == 1) ? 0 : 128;
            __bf16* dstbuf = (p == 0 || p == 3) ? q2 : k2;
            #pragma unroll
            for (int g = 0; g < 4; ++g) {
                int n = n0 + g * 32 + lo, h = n >> 7, d = n & 127;
                float bn = bias[n];
                __bf16* dp = dstbuf + (((size_t)(b * H_ + h)) * S_ + s0 + 4 * hi) * 256 + off + d;
                #pragma unroll
                for (int r = 0; r < 16; ++r)
                    dp[((r & 3) + 8 * (r >> 2)) * 256] = f2b((acc[g][r] + bn) * sc);
            }
        }
    } else {
        // v_out = V @ W_comb^T + bias_comb
        int bx2 = bx - 2560;
        int m0 = bx2 * 128 + w * 32;
        const __bf16* wc = (const __bf16*)(ws + WS_WCMB);
        const float*  bc = (const float*)(ws + WS_BCMB);
        f32x16 acc[4];
        #pragma unroll
        for (int g = 0; g < 4; ++g)
            #pragma unroll
            for (int i = 0; i < 16; ++i) acc[g][i] = 0.f;
        const float* arow = Vin + (size_t)(m0 + lo) * 128;
        #pragma unroll
        for (int ks = 0; ks < 8; ++ks) {
            int kb = ks * 16 + hi * 8;
            f32x4 a0 = *(const f32x4*)(arow + kb);
            f32x4 a1 = *(const f32x4*)(arow + kb + 4);
            bf16x8 af = cvt8(a0, a1);
            #pragma unroll
            for (int g = 0; g < 4; ++g) {
                bf16x8 bf = *(const bf16x8*)&wc[(size_t)(g * 32 + lo) * 128 + kb];
                acc[g] = __builtin_amdgcn_mfma_f32_32x32x16_bf16(af, bf, acc[g], 0, 0, 0);
            }
        }
        #pragma unroll
        for (int g = 0; g < 4; ++g) {
            int n = g * 32 + lo;
            float bn = bc[n];
            float* op = out + 1048576 + (size_t)(m0 + 4 * hi) * 128 + n;
            #pragma unroll
            for (int r = 0; r < 16; ++r)
                op[((r & 3) + 8 * (r >> 2)) * 128] = acc[g][r] + bn;
        }
    }
}

// ---------------- flash attention: 32x32 MFMA, swapped operands ----------------
__global__ __launch_bounds__(256, 2) void k_attn(char* ws) {
    __shared__ __align__(16) __bf16 Ks[2][64 * 256];   // double-buffered K, src-preswizzled
    __shared__ __align__(16) __bf16 VTs[128 * 64];     // V^T tile, swizzled
    const __bf16* q2 = (const __bf16*)(ws + WS_Q2);
    const __bf16* k2 = (const __bf16*)(ws + WS_K2);
    const __bf16* vT = (const __bf16*)(ws + WS_VT);
    __bf16* ctxg = (__bf16*)(ws + WS_CTX);

    int bx = blockIdx.x;
    int idx = bx >> 3;
    int bh = (bx & 7) * 4 + (idx >> 4);   // XCD-chunked: 4 heads per XCD
    int qt = idx & 15;
    int t = threadIdx.x, lane = t & 63, w = t >> 6;
    int lo = lane & 31, hi = lane >> 5;

    const __bf16* k2b = k2 + (size_t)bh * S_ * 256;
    const __bf16* vTb = vT + (size_t)bh * 128 * S_;
    int q0 = qt * 128;
    int qrow = q0 + w * 32 + lo;

    bf16x8 qf[16];
    {
        const __bf16* qp = q2 + ((size_t)bh * S_ + qrow) * 256 + hi * 8;
        #pragma unroll
        for (int ks = 0; ks < 16; ++ks) qf[ks] = *(const bf16x8*)(qp + ks * 16);
    }

    f32x16 ctx[4];
    #pragma unroll
    for (int i = 0; i < 4; ++i)
        #pragma unroll
        for (int j = 0; j < 16; ++j) ctx[i][j] = 0.f;
    float m_r = -1e30f, l_r = 0.f;

    bf16x8 vreg[4];

    // prologue: tile 0
    {
        #pragma unroll
        for (int i = 0; i < 8; ++i) {
            int r0 = w * 16 + i * 2;
            int row = r0 + hi;
            const __bf16* src = k2b + (size_t)row * 256 + (((lane & 31) ^ (row & 7)) << 3);
            gload16(src, &Ks[0][r0 * 256]);
        }
        #pragma unroll
        for (int i = 0; i < 4; ++i) {
            int d = i * 32 + (t >> 3), kb = t & 7;
            vreg[i] = *(const bf16x8*)(vTb + (size_t)d * S_ + kb * 8);
        }
        #pragma unroll
        for (int i = 0; i < 4; ++i) {
            int d = i * 32 + (t >> 3), kb = t & 7;
            *(bf16x8*)&VTs[d * 64 + ((kb ^ (d & 7)) << 3)] = vreg[i];
        }
    }
    __syncthreads();

    int cur = 0;
    for (int kt = 0; kt < 32; ++kt) {
        bool pre = (kt + 1 < 32);
        if (pre) {
            #pragma unroll
            for (int i = 0; i < 8; ++i) {
                int r0 = w * 16 + i * 2;
                int row = r0 + hi;
                const __bf16* src = k2b + (size_t)((kt + 1) * 64 + row) * 256 +
                                    (((lane & 31) ^ (row & 7)) << 3);
                gload16(src, &Ks[cur ^ 1][r0 * 256]);
            }
            #pragma unroll
            for (int i = 0; i < 4; ++i) {
                int d = i * 32 + (t >> 3), kb = t & 7;
                vreg[i] = *(const bf16x8*)(vTb + (size_t)d * S_ + (kt + 1) * 64 + kb * 8);
            }
        }

        // ---- QK^T (swapped) ----
        f32x16 s0, s1;
        #pragma unroll
        for (int j = 0; j < 16; ++j) { s0[j] = 0.f; s1[j] = 0.f; }
        int xm = lo & 7;
        __builtin_amdgcn_s_setprio(1);
        #pragma unroll
        for (int ks = 0; ks < 16; ++ks) {
            bf16x8 a0 = *(const bf16x8*)&Ks[cur][lo * 256 + (((2 * ks + hi) ^ xm) << 3)];
            bf16x8 a1 = *(const bf16x8*)&Ks[cur][(32 + lo) * 256 + (((2 * ks + hi) ^ xm) << 3)];
            s0 = __builtin_amdgcn_mfma_f32_32x32x16_bf16(a0, qf[ks], s0, 0, 0, 0);
            s1 = __builtin_amdgcn_mfma_f32_32x32x16_bf16(a1, qf[ks], s1, 0, 0, 0);
        }
        __builtin_amdgcn_s_setprio(0);

        // ---- online softmax with defer-max (log2 units) ----
        float pm = -1e30f;
        #pragma unroll
        for (int j = 0; j < 16; ++j) pm = fmaxf(pm, fmaxf(s0[j], s1[j]));
        pm = fmaxf(pm, __shfl_xor(pm, 32));
        if (!__all(pm - m_r <= 11.0f)) {
            float mn = fmaxf(m_r, pm);
            float alpha = fexp2(m_r - mn);
            m_r = mn;
            l_r *= alpha;
            #pragma unroll
            for (int i = 0; i < 4; ++i)
                #pragma unroll
                for (int j = 0; j < 16; ++j) ctx[i][j] *= alpha;
        }
        float psum = 0.f;
        #pragma unroll
        for (int j = 0; j < 16; ++j) {
            s0[j] = fexp2(s0[j] - m_r); psum += s0[j];
            s1[j] = fexp2(s1[j] - m_r); psum += s1[j];
        }
        psum += __shfl_xor(psum, 32);
        l_r += psum;

        // ---- pack P into B-fragments ----
        bf16x8 pf[4];
        PACKP(pf[0], s0[0], s0[1], s0[2], s0[3], s0[4], s0[5], s0[6], s0[7]);
        PACKP(pf[1], s0[8], s0[9], s0[10], s0[11], s0[12], s0[13], s0[14], s0[15]);
        PACKP(pf[2], s1[0], s1[1], s1[2], s1[3], s1[4], s1[5], s1[6], s1[7]);
        PACKP(pf[3], s1[8], s1[9], s1[10], s1[11], s1[12], s1[13], s1[14], s1[15]);

        // ---- PV (swapped): ctx^T[d][q] += V^T x P ----
        __builtin_amdgcn_s_setprio(1);
        #pragma unroll
        for (int kp = 0; kp < 4; ++kp) {
            #pragma unroll
            for (int ds = 0; ds < 4; ++ds) {
                int row = ds * 32 + lo;
                bf16x8 va = *(const bf16x8*)&VTs[row * 64 + (((2 * kp + hi) ^ xm) << 3)];
                ctx[ds] = __builtin_amdgcn_mfma_f32_32x32x16_bf16(va, pf[kp], ctx[ds], 0, 0, 0);
            }
        }
        __builtin_amdgcn_s_setprio(0);

        __syncthreads();
        if (pre) {
            #pragma unroll
            for (int i = 0; i < 4; ++i) {
                int d = i * 32 + (t >> 3), kb = t & 7;
                *(bf16x8*)&VTs[d * 64 + ((kb ^ (d & 7)) << 3)] = vreg[i];
            }
        }
        __syncthreads();
        cur ^= 1;
    }

    // ---- epilogue ----
    __syncthreads();
    __bf16* sc = &Ks[0][0] + w * 4096;
    float inv = 1.f / l_r;
    #pragma unroll
    for (int ds = 0; ds < 4; ++ds) {
        #pragma unroll
        for (int g = 0; g < 4; ++g) {
            #pragma unroll
            for (int h2 = 0; h2 < 2; ++h2) {
                int r = g * 4 + h2 * 2;
                unsigned pv = pk2(ctx[ds][r] * inv, ctx[ds][r + 1] * inv);
                int d = ds * 32 + (r & 3) + 8 * (r >> 2) + 4 * hi;
                *(unsigned*)&sc[lo * 128 + (((d >> 3) ^ (lo & 7)) << 3) + (d & 7)] = pv;
            }
        }
    }
    __syncthreads();
    {
        int b = bh >> 3, h = bh & 7;
        int qq = lane >> 1, half = lane & 1;
        int srow = q0 + w * 32 + qq;
        #pragma unroll
        for (int j = 0; j < 8; ++j) {
            int d8 = half * 8 + j;
            bf16x8 vv = *(const bf16x8*)&sc[qq * 128 + ((d8 ^ (qq & 7)) << 3)];
            *(bf16x8*)&ctxg[((size_t)(b * S_ + srow)) * 1024 + h * 128 + d8 * 8] = vv;
        }
    }
}

// ---------------- out = LN(ctx @ qlin^T + qlin_b + Q), single-wave blocks ----------
__global__ __launch_bounds__(64) void k_out(const float* Qin, const float* qlin_b,
                                            const float* ln_g, const float* ln_b,
                                            char* ws, float* out) {
    int t = threadIdx.x, lo = t & 31, hi = t >> 5;
    int m0 = blockIdx.x * 32;
    const __bf16* ctx = (const __bf16*)(ws + WS_CTX);
    const __bf16* qlb = (const __bf16*)(ws + WS_QLIN);
    f32x16 acc[4];
    #pragma unroll
    for (int g = 0; g < 4; ++g)
        #pragma unroll
        for (int i = 0; i < 16; ++i) acc[g][i] = 0.f;
    const __bf16* arow = ctx + (size_t)(m0 + lo) * 1024;
    #pragma unroll 8
    for (int ks = 0; ks < 64; ++ks) {
        int kb = ks * 16 + hi * 8;
        bf16x8 af = *(const bf16x8*)(arow + kb);
        #pragma unroll
        for (int g = 0; g < 4; ++g) {
            bf16x8 bf = *(const bf16x8*)&qlb[(size_t)(g * 32 + lo) * 1024 + kb];
            acc[g] = __builtin_amdgcn_mfma_f32_32x32x16_bf16(af, bf, acc[g], 0, 0, 0);
        }
    }
    float gb[4], bb[4], qb[4];
    #pragma unroll
    for (int g = 0; g < 4; ++g) {
        int n = g * 32 + lo;
        gb[g] = ln_g[n]; bb[g] = ln_b[n]; qb[g] = qlin_b[n];
    }
    const float* qp = Qin + (size_t)(m0 + 4 * hi) * 128;
    float* op = out + (size_t)(m0 + 4 * hi) * 128;
    #pragma unroll
    for (int r = 0; r < 16; ++r) {
        int ro = ((r & 3) + 8 * (r >> 2)) * 128;
        float x[4];
        float sum = 0.f;
        #pragma unroll
        for (int g = 0; g < 4; ++g) {
            x[g] = acc[g][r] + qb[g] + qp[ro + g * 32 + lo];
            sum += x[g];
        }
        sum += __shfl_xor(sum, 1);
        sum += __shfl_xor(sum, 2);
        sum += __shfl_xor(sum, 4);
        sum += __shfl_xor(sum, 8);
        sum += __shfl_xor(sum, 16);
        float mean = sum * (1.f / 128.f);
        float sq = 0.f;
        #pragma unroll
        for (int g = 0; g < 4; ++g) {
            float d = x[g] - mean;
            sq += d * d;
        }
        sq += __shfl_xor(sq, 1);
        sq += __shfl_xor(sq, 2);
        sq += __shfl_xor(sq, 4);
        sq += __shfl_xor(sq, 8);
        sq += __shfl_xor(sq, 16);
        float rstd = rsqrtf(sq * (1.f / 128.f) + 1e-5f);
        #pragma unroll
        for (int g = 0; g < 4; ++g)
            op[ro + g * 32 + lo] = (x[g] - mean) * rstd * gb[g] + bb[g];
    }
}

extern "C" void kernel_launch(void* const* d_in, const int* in_sizes, int n_in,
                              void* d_out, int out_size, void* d_ws, size_t ws_size,
                              hipStream_t stream) {
    (void)in_sizes; (void)n_in; (void)out_size; (void)ws_size;
    const float* Q    = (const float*)d_in[0];
    const float* K    = (const float*)d_in[1];
    const float* V    = (const float*)d_in[2];
    const float* QP   = (const float*)d_in[3];
    const float* KP   = (const float*)d_in[4];
    const float* WQw  = (const float*)d_in[6];
    const float* WQb  = (const float*)d_in[7];
    const float* WKw  = (const float*)d_in[8];
    const float* WKb  = (const float*)d_in[9];
    const float* WVw  = (const float*)d_in[10];
    const float* WVb  = (const float*)d_in[11];
    const float* WQPw = (const float*)d_in[12];
    const float* WQPb = (const float*)d_in[13];
    const float* WKPw = (const float*)d_in[14];
    const float* WKPb = (const float*)d_in[15];
    const float* qlw  = (const float*)d_in[18];
    const float* qlb  = (const float*)d_in[19];
    const float* vlw  = (const float*)d_in[20];
    const float* vlb  = (const float*)d_in[21];
    const float* lng  = (const float*)d_in[22];
    const float* lnb  = (const float*)d_in[23];
    char* ws = (char*)d_ws;
    float* out = (float*)d_out;

    k_prep<<<388, 256, 0, stream>>>(WQw, WKw, WVw, WQPw, WKPw, qlw, vlw, WVb, vlb, ws);
    k_proj<<<2624, 256, 0, stream>>>(Q, K, V, QP, KP, WQb, WKb, WVb, WQPb, WKPb, ws, out);
    k_attn<<<512, 256, 0, stream>>>(ws);
    k_out<<<256, 64, 0, stream>>>(Q, qlb, lng, lnb, ws, out);
}

// Round 4
// 238.429 us; speedup vs baseline: 2.7193x; 1.0788x over previous
//
#include <hip/hip_runtime.h>

typedef __attribute__((ext_vector_type(8))) __bf16 bf16x8;
typedef __attribute__((ext_vector_type(4))) float f32x4;
typedef __attribute__((ext_vector_type(16))) float f32x16;
typedef __attribute__((ext_vector_type(4))) unsigned int u32x4;
typedef unsigned char u8;

#define DEV static __device__ __forceinline__

constexpr int B_ = 4, S_ = 2048, H_ = 8;
// scores computed on (q*32, k*32) fp8 inputs; c converts raw dot -> log2-domain
constexpr float C_LOG = 0.08838834764831845f * 1.4426950408889634f / 1024.0f;
constexpr float THR_RAW = 3.0f / C_LOG;   // defer-max threshold (3 log2 units)

// workspace layout (bytes)
constexpr size_t WS_Q2   = 0;                                  // fp8 [B,H,S,256] (q|qp)*32
constexpr size_t WS_K2   = WS_Q2  + (size_t)B_*H_*S_*256;      // fp8 [B,H,S,256] (k|kp)*32
constexpr size_t WS_VT   = WS_K2  + (size_t)B_*H_*S_*256;      // fp8 [B,H,128,S] (V^T)*16
constexpr size_t WS_CTX  = WS_VT  + (size_t)B_*H_*S_*128;      // bf16 [B,S,1024]
constexpr size_t WS_WBF  = WS_CTX + (size_t)B_*S_*1024*2;      // bf16 5 x [1024,128]
constexpr size_t WS_QLIN = WS_WBF + (size_t)5*1024*128*2;      // bf16 [128,1024]
constexpr size_t WS_WCMB = WS_QLIN + (size_t)128*1024*2;       // bf16 [128,128]
constexpr size_t WS_BCMB = WS_WCMB + (size_t)128*128*2;        // f32  [128]

DEV __bf16 f2b(float f) {
    unsigned u = __builtin_bit_cast(unsigned, f);
    unsigned r = u + 0x7fffu + ((u >> 16) & 1u);
    unsigned short h = (unsigned short)(r >> 16);
    return __builtin_bit_cast(__bf16, h);
}

DEV float fexp2(float x) {
#if __has_builtin(__builtin_amdgcn_exp2f)
    return __builtin_amdgcn_exp2f(x);
#else
    return exp2f(x);
#endif
}

DEV unsigned pk2(float a, float b) {
    unsigned r;
    asm("v_cvt_pk_bf16_f32 %0, %1, %2" : "=v"(r) : "v"(a), "v"(b));
    return r;
}

DEV bf16x8 cvt8(f32x4 a, f32x4 b) {
    u32x4 u{pk2(a[0], a[1]), pk2(a[2], a[3]), pk2(b[0], b[1]), pk2(b[2], b[3])};
    return __builtin_bit_cast(bf16x8, u);
}

DEV unsigned pkf8(float a, float b) {
    return (unsigned)__builtin_amdgcn_cvt_pk_fp8_f32(a, b, 0, false);
}
DEV unsigned pkf8h(unsigned old, float a, float b) {
    return (unsigned)__builtin_amdgcn_cvt_pk_fp8_f32(a, b, (int)old, true);
}
DEV u8 f2f8(float a) { return (u8)(pkf8(a, a) & 0xffu); }

DEV void gload16(const void* g, void* l) {
    __builtin_amdgcn_global_load_lds(
        (const __attribute__((address_space(1))) unsigned int*)g,
        (__attribute__((address_space(3))) unsigned int*)l, 16, 0, 0);
}

DEV f32x16 mfma8(long a, long b, f32x16 c) {
    return __builtin_amdgcn_mfma_f32_32x32x16_fp8_fp8(a, b, c, 0, 0, 0);
}

// P fp8 B-fragment for one 16-key window from 8 score regs (crow order)
#define PACK16(dst, sv, base) { \
    unsigned A4 = pkf8(sv[base+0], sv[base+1]); A4 = pkf8h(A4, sv[base+2], sv[base+3]); \
    unsigned B4 = pkf8(sv[base+4], sv[base+5]); B4 = pkf8h(B4, sv[base+6], sv[base+7]); \
    asm("v_permlane32_swap_b32 %0, %1" : "+v"(B4), "+v"(A4)); \
    dst = (long)(((unsigned long)B4 << 32) | (unsigned long)A4); }

// ---------------- prep: weights->bf16 (bx<384) + W_comb MFMA (bx>=384) -------------
__global__ __launch_bounds__(256) void k_prep(const float* wq, const float* wk,
                                              const float* wv, const float* wqp,
                                              const float* wkp, const float* qlin,
                                              const float* vlin_w, const float* wv_b,
                                              const float* vlin_b, char* ws) {
    int bx = blockIdx.x, t = threadIdx.x;
    if (bx < 384) {
        __bf16* wbf = (__bf16*)(ws + WS_WBF);
        __bf16* qlb = (__bf16*)(ws + WS_QLIN);
        size_t i8 = ((size_t)bx * 256 + t) * 8;
        if (i8 < 655360) {
            int p = (int)(i8 >> 17);
            size_t e = i8 & 131071;
            const float* src = p == 0 ? wq : p == 1 ? wk : p == 2 ? wv : p == 3 ? wqp : wkp;
            f32x4 a = *(const f32x4*)(src + e);
            f32x4 b = *(const f32x4*)(src + e + 4);
            *(bf16x8*)(wbf + i8) = cvt8(a, b);
        } else {
            size_t e = i8 - 655360;
            f32x4 a = *(const f32x4*)(qlin + e);
            f32x4 b = *(const f32x4*)(qlin + e + 4);
            *(bf16x8*)(qlb + e) = cvt8(a, b);
        }
    } else {
        __bf16* wc = (__bf16*)(ws + WS_WCMB);
        float*  bc = (float*)(ws + WS_BCMB);
        int mb = bx - 384;
        int m0 = mb * 32;
        int lane = t & 63, w = t >> 6, lo = lane & 31, hi = lane >> 5;
        int j = w * 32 + lo;
        f32x16 acc;
        #pragma unroll
        for (int i = 0; i < 16; ++i) acc[i] = 0.f;
        const float* arow = vlin_w + (size_t)(m0 + lo) * 1024;
        #pragma unroll 4
        for (int ks = 0; ks < 64; ++ks) {
            int kb = ks * 16 + hi * 8;
            f32x4 a0 = *(const f32x4*)(arow + kb);
            f32x4 a1 = *(const f32x4*)(arow + kb + 4);
            bf16x8 af = cvt8(a0, a1);
            const float* wp = wv + (size_t)kb * 128 + j;
            u32x4 u{pk2(wp[0], wp[128]), pk2(wp[256], wp[384]),
                    pk2(wp[512], wp[640]), pk2(wp[768], wp[896])};
            bf16x8 bf = __builtin_bit_cast(bf16x8, u);
            acc = __builtin_amdgcn_mfma_f32_32x32x16_bf16(af, bf, acc, 0, 0, 0);
        }
        __bf16* wp2 = wc + (size_t)(m0 + 4 * hi) * 128 + j;
        #pragma unroll
        for (int r = 0; r < 16; ++r)
            wp2[((r & 3) + 8 * (r >> 2)) * 128] = f2b(acc[r]);
        int i = m0 + (t >> 3), part = t & 7;
        float s = 0.f;
        const float* vr = vlin_w + (size_t)i * 1024 + part * 128;
        const float* br = wv_b + part * 128;
        #pragma unroll 8
        for (int kk = 0; kk < 32; ++kk) {
            f32x4 a = *(const f32x4*)(vr + kk * 4);
            f32x4 b = *(const f32x4*)(br + kk * 4);
            s += a[0]*b[0] + a[1]*b[1] + a[2]*b[2] + a[3]*b[3];
        }
        s += __shfl_xor(s, 1);
        s += __shfl_xor(s, 2);
        s += __shfl_xor(s, 4);
        if (part == 0) bc[i] = s + vlin_b[i];
    }
}

// ---------------- projections (XCD-grouped, LDS-free direct MFMA) + v_out ----------
__global__ __launch_bounds__(256) void k_proj(const float* Qin, const float* Kin,
                                              const float* Vin, const float* QPin,
                                              const float* KPin,
                                              const float* bq, const float* bk,
                                              const float* bv, const float* bqp,
                                              const float* bkp, char* ws, float* out) {
    int bx = blockIdx.x, t = threadIdx.x;
    int lane = t & 63, w = t >> 6, lo = lane & 31, hi = lane >> 5;
    int xcd = bx & 7, seq = bx >> 3;
    u8* q2  = (u8*)(ws + WS_Q2);
    u8* k2  = (u8*)(ws + WS_K2);
    u8* vbT = (u8*)(ws + WS_VT);
    if (seq < 320) {
        int T = (seq & ~7) + xcd;          // all 8 N-chunks of tile T on same XCD
        int nq = seq & 7;
        int p = T >> 6, mt = T & 63;
        int m0 = mt * 128 + w * 32, n0 = nq * 128;
        const float* src  = p == 0 ? Qin : p == 1 ? Kin : p == 2 ? Vin : p == 3 ? QPin : KPin;
        const float* bias = p == 0 ? bq  : p == 1 ? bk  : p == 2 ? bv  : p == 3 ? bqp  : bkp;
        const __bf16* wb = (const __bf16*)(ws + WS_WBF) + (size_t)p * 131072;
        f32x16 acc[4];
        #pragma unroll
        for (int g = 0; g < 4; ++g)
            #pragma unroll
            for (int i = 0; i < 16; ++i) acc[g][i] = 0.f;
        const float* arow = src + (size_t)(m0 + lo) * 128;
        #pragma unroll
        for (int ks = 0; ks < 8; ++ks) {
            int kb = ks * 16 + hi * 8;
            f32x4 a0 = *(const f32x4*)(arow + kb);
            f32x4 a1 = *(const f32x4*)(arow + kb + 4);
            bf16x8 af = cvt8(a0, a1);
            #pragma unroll
            for (int g = 0; g < 4; ++g) {
                bf16x8 bf = *(const bf16x8*)&wb[(size_t)(n0 + g * 32 + lo) * 128 + kb];
                acc[g] = __builtin_amdgcn_mfma_f32_32x32x16_bf16(af, bf, acc[g], 0, 0, 0);
            }
        }
        int b = m0 >> 11, s0 = m0 & 2047;
        if (p == 2) {
            #pragma unroll
            for (int g = 0; g < 4; ++g) {
                int n = n0 + g * 32 + lo, h = n >> 7, d = n & 127;
                float bn = bias[n];
                u8* dp = vbT + (((size_t)(b * H_ + h)) * 128 + d) * (size_t)S_ + s0 + 4 * hi;
                #pragma unroll
                for (int rq = 0; rq < 4; ++rq) {
                    unsigned wd = pkf8((acc[g][rq*4+0] + bn) * 16.f,
                                       (acc[g][rq*4+1] + bn) * 16.f);
                    wd = pkf8h(wd, (acc[g][rq*4+2] + bn) * 16.f,
                                   (acc[g][rq*4+3] + bn) * 16.f);
                    *(unsigned*)&dp[rq * 8] = wd;
                }
            }
        } else {
            int off = (p == 0 || p == 1) ? 0 : 128;
            u8* dstbuf = (p == 0 || p == 3) ? q2 : k2;
            #pragma unroll
            for (int g = 0; g < 4; ++g) {
                int n = n0 + g * 32 + lo, h = n >> 7, d = n & 127;
                float bn = bias[n];
                u8* dp = dstbuf + (((size_t)(b * H_ + h)) * S_ + s0 + 4 * hi) * 256 + off + d;
                #pragma unroll
                for (int r = 0; r < 16; ++r)
                    dp[((r & 3) + 8 * (r >> 2)) * 256] = f2f8((acc[g][r] + bn) * 32.f);
            }
        }
    } else {
        int T2 = (seq - 320) * 8 + xcd;
        int m0 = T2 * 128 + w * 32;
        const __bf16* wc = (const __bf16*)(ws + WS_WCMB);
        const float*  bc = (const float*)(ws + WS_BCMB);
        f32x16 acc[4];
        #pragma unroll
        for (int g = 0; g < 4; ++g)
            #pragma unroll
            for (int i = 0; i < 16; ++i) acc[g][i] = 0.f;
        const float* arow = Vin + (size_t)(m0 + lo) * 128;
        #pragma unroll
        for (int ks = 0; ks < 8; ++ks) {
            int kb = ks * 16 + hi * 8;
            f32x4 a0 = *(const f32x4*)(arow + kb);
            f32x4 a1 = *(const f32x4*)(arow + kb + 4);
            bf16x8 af = cvt8(a0, a1);
            #pragma unroll
            for (int g = 0; g < 4; ++g) {
                bf16x8 bf = *(const bf16x8*)&wc[(size_t)(g * 32 + lo) * 128 + kb];
                acc[g] = __builtin_amdgcn_mfma_f32_32x32x16_bf16(af, bf, acc[g], 0, 0, 0);
            }
        }
        #pragma unroll
        for (int g = 0; g < 4; ++g) {
            int n = g * 32 + lo;
            float bn = bc[n];
            float* op = out + 1048576 + (size_t)(m0 + 4 * hi) * 128 + n;
            #pragma unroll
            for (int r = 0; r < 16; ++r)
                op[((r & 3) + 8 * (r >> 2)) * 128] = acc[g][r] + bn;
        }
    }
}

// ---------------- flash attention: fp8, 32x32 MFMA, swapped operands ----------------
__global__ __launch_bounds__(256, 2) void k_attn(char* ws) {
    __shared__ __align__(16) u8 Ks[2][64 * 256];   // fp8 K dbuf, src-preswizzled (16KB ea)
    __shared__ __align__(16) u8 VTs[128 * 64];     // fp8 V^T tile, swizzled (8KB)
    const u8* q2 = (const u8*)(ws + WS_Q2);
    const u8* k2 = (const u8*)(ws + WS_K2);
    const u8* vT = (const u8*)(ws + WS_VT);
    __bf16* ctxg = (__bf16*)(ws + WS_CTX);

    int bx = blockIdx.x;
    int idx = bx >> 3;
    int bh = (bx & 7) * 4 + (idx >> 4);   // XCD-chunked heads
    int qt = idx & 15;
    int t = threadIdx.x, lane = t & 63, w = t >> 6;
    int lo = lane & 31, hi = lane >> 5;
    int xm = lo & 7;

    const u8* k2b = k2 + (size_t)bh * S_ * 256;
    const u8* vTb = vT + (size_t)bh * 128 * S_;
    int q0 = qt * 128;
    int qrow = q0 + w * 32 + lo;

    long qf[16];
    {
        const u8* qp = q2 + ((size_t)bh * S_ + qrow) * 256 + hi * 8;
        #pragma unroll
        for (int ks = 0; ks < 16; ++ks) qf[ks] = *(const long*)(qp + ks * 16);
    }

    f32x16 ctx[4];
    #pragma unroll
    for (int i = 0; i < 4; ++i)
        #pragma unroll
        for (int j = 0; j < 16; ++j) ctx[i][j] = 0.f;
    float m_r = -1e30f, l_r = 0.f;

    long vreg[4];
    int kt0 = ((bx >> 8) & 1) << 4;   // phase-stagger co-resident blocks

    // prologue: tile kt0
    {
        #pragma unroll
        for (int i = 0; i < 4; ++i) {
            int idx16 = i * 256 + t;
            int row = idx16 >> 4, blk = idx16 & 15;
            const u8* src = k2b + (size_t)(kt0 * 64 + row) * 256 + ((blk ^ (row & 7)) << 4);
            gload16(src, &Ks[0][(i * 256 + w * 64) * 16]);
        }
        #pragma unroll
        for (int i = 0; i < 4; ++i) {
            int d = i * 32 + (t >> 3), kb = t & 7;
            vreg[i] = *(const long*)(vTb + (size_t)d * S_ + kt0 * 64 + kb * 8);
        }
        #pragma unroll
        for (int i = 0; i < 4; ++i) {
            int d = i * 32 + (t >> 3), kb = t & 7;
            *(long*)&VTs[d * 64 + ((kb ^ (d & 7)) << 3)] = vreg[i];
        }
    }
    __syncthreads();

    int cur = 0;
    for (int it = 0; it < 32; ++it) {
        bool pre = (it + 1 < 32);
        int ktn = (kt0 + it + 1) & 31;
        if (pre) {
            #pragma unroll
            for (int i = 0; i < 4; ++i) {
                int idx16 = i * 256 + t;
                int row = idx16 >> 4, blk = idx16 & 15;
                const u8* src = k2b + (size_t)(ktn * 64 + row) * 256 + ((blk ^ (row & 7)) << 4);
                gload16(src, &Ks[cur ^ 1][(i * 256 + w * 64) * 16]);
            }
            #pragma unroll
            for (int i = 0; i < 4; ++i) {
                int d = i * 32 + (t >> 3), kb = t & 7;
                vreg[i] = *(const long*)(vTb + (size_t)d * S_ + ktn * 64 + kb * 8);
            }
        }

        // ---- QK^T (swapped, fp8) ----
        f32x16 s0, s1;
        #pragma unroll
        for (int j = 0; j < 16; ++j) { s0[j] = 0.f; s1[j] = 0.f; }
        __builtin_amdgcn_s_setprio(1);
        #pragma unroll
        for (int ks = 0; ks < 16; ++ks) {
            long a0 = *(const long*)&Ks[cur][lo * 256 + ((ks ^ xm) << 4) + hi * 8];
            long a1 = *(const long*)&Ks[cur][(32 + lo) * 256 + ((ks ^ xm) << 4) + hi * 8];
            s0 = mfma8(a0, qf[ks], s0);
            s1 = mfma8(a1, qf[ks], s1);
        }
        __builtin_amdgcn_s_setprio(0);

        // ---- online softmax (raw units; c folds into fma) ----
        float pm = -3e38f;
        #pragma unroll
        for (int j = 0; j < 16; ++j) pm = fmaxf(pm, fmaxf(s0[j], s1[j]));
        pm = fmaxf(pm, __shfl_xor(pm, 32));
        if (!__all(pm - m_r <= THR_RAW)) {
            float mn = fmaxf(m_r, pm);
            float alpha = fexp2((m_r - mn) * C_LOG);
            m_r = mn;
            l_r *= alpha;
            #pragma unroll
            for (int i = 0; i < 4; ++i)
                #pragma unroll
                for (int j = 0; j < 16; ++j) ctx[i][j] *= alpha;
        }
        float kc = 4.0f - m_r * C_LOG;   // P' = exp2((s-m)*c + 4) in [0,128]
        float psum = 0.f;
        #pragma unroll
        for (int j = 0; j < 16; ++j) {
            s0[j] = fexp2(fmaf(s0[j], C_LOG, kc)); psum += s0[j];
            s1[j] = fexp2(fmaf(s1[j], C_LOG, kc)); psum += s1[j];
        }
        psum += __shfl_xor(psum, 32);
        l_r += psum;

        // ---- P -> fp8 B-fragments ----
        long pf[4];
        PACK16(pf[0], s0, 0);
        PACK16(pf[1], s0, 8);
        PACK16(pf[2], s1, 0);
        PACK16(pf[3], s1, 8);

        // ---- PV (swapped): ctx^T[d][q] += V^T x P ----
        __builtin_amdgcn_s_setprio(1);
        #pragma unroll
        for (int kp = 0; kp < 4; ++kp) {
            #pragma unroll
            for (int ds = 0; ds < 4; ++ds) {
                int row = ds * 32 + lo;
                long va = *(const long*)&VTs[row * 64 + (((2 * kp + hi) ^ xm) << 3)];
                ctx[ds] = mfma8(va, pf[kp], ctx[ds]);
            }
        }
        __builtin_amdgcn_s_setprio(0);

        __syncthreads();
        if (pre) {
            #pragma unroll
            for (int i = 0; i < 4; ++i) {
                int d = i * 32 + (t >> 3), kb = t & 7;
                *(long*)&VTs[d * 64 + ((kb ^ (d & 7)) << 3)] = vreg[i];
            }
        }
        __syncthreads();
        cur ^= 1;
    }

    // ---- epilogue: /(16*l), LDS bounce, coalesced bf16 write ----
    __syncthreads();
    __bf16* sc = (__bf16*)&Ks[0][0] + w * 4096;
    float inv = 1.f / (16.f * l_r);
    #pragma unroll
    for (int ds = 0; ds < 4; ++ds) {
        #pragma unroll
        for (int g = 0; g < 4; ++g) {
            #pragma unroll
            for (int h2 = 0; h2 < 2; ++h2) {
                int r = g * 4 + h2 * 2;
                unsigned pv = pk2(ctx[ds][r] * inv, ctx[ds][r + 1] * inv);
                int d = ds * 32 + (r & 3) + 8 * (r >> 2) + 4 * hi;
                *(unsigned*)&sc[lo * 128 + (((d >> 3) ^ (lo & 7)) << 3) + (d & 7)] = pv;
            }
        }
    }
    __syncthreads();
    {
        int b = bh >> 3, h = bh & 7;
        int qq = lane >> 1, half = lane & 1;
        int srow = q0 + w * 32 + qq;
        #pragma unroll
        for (int j = 0; j < 8; ++j) {
            int d8 = half * 8 + j;
            bf16x8 vv = *(const bf16x8*)&sc[qq * 128 + ((d8 ^ (qq & 7)) << 3)];
            *(bf16x8*)&ctxg[((size_t)(b * S_ + srow)) * 1024 + h * 128 + d8 * 8] = vv;
        }
    }
}

// ---------------- out = LN(ctx @ qlin^T + qlin_b + Q), single-wave blocks ----------
__global__ __launch_bounds__(64) void k_out(const float* Qin, const float* qlin_b,
                                            const float* ln_g, const float* ln_b,
                                            char* ws, float* out) {
    int t = threadIdx.x, lo = t & 31, hi = t >> 5;
    int m0 = blockIdx.x * 32;
    const __bf16* ctx = (const __bf16*)(ws + WS_CTX);
    const __bf16* qlb = (const __bf16*)(ws + WS_QLIN);
    f32x16 acc[4];
    #pragma unroll
    for (int g = 0; g < 4; ++g)
        #pragma unroll
        for (int i = 0; i < 16; ++i) acc[g][i] = 0.f;
    const __bf16* arow = ctx + (size_t)(m0 + lo) * 1024;
    #pragma unroll 8
    for (int ks = 0; ks < 64; ++ks) {
        int kb = ks * 16 + hi * 8;
        bf16x8 af = *(const bf16x8*)(arow + kb);
        #pragma unroll
        for (int g = 0; g < 4; ++g) {
            bf16x8 bf = *(const bf16x8*)&qlb[(size_t)(g * 32 + lo) * 1024 + kb];
            acc[g] = __builtin_amdgcn_mfma_f32_32x32x16_bf16(af, bf, acc[g], 0, 0, 0);
        }
    }
    float gb[4], bb[4], qb[4];
    #pragma unroll
    for (int g = 0; g < 4; ++g) {
        int n = g * 32 + lo;
        gb[g] = ln_g[n]; bb[g] = ln_b[n]; qb[g] = qlin_b[n];
    }
    const float* qp = Qin + (size_t)(m0 + 4 * hi) * 128;
    float* op = out + (size_t)(m0 + 4 * hi) * 128;
    #pragma unroll
    for (int r = 0; r < 16; ++r) {
        int ro = ((r & 3) + 8 * (r >> 2)) * 128;
        float x[4];
        float sum = 0.f;
        #pragma unroll
        for (int g = 0; g < 4; ++g) {
            x[g] = acc[g][r] + qb[g] + qp[ro + g * 32 + lo];
            sum += x[g];
        }
        sum += __shfl_xor(sum, 1);
        sum += __shfl_xor(sum, 2);
        sum += __shfl_xor(sum, 4);
        sum += __shfl_xor(sum, 8);
        sum += __shfl_xor(sum, 16);
        float mean = sum * (1.f / 128.f);
        float sq = 0.f;
        #pragma unroll
        for (int g = 0; g < 4; ++g) {
            float d = x[g] - mean;
            sq += d * d;
        }
        sq += __shfl_xor(sq, 1);
        sq += __shfl_xor(sq, 2);
        sq += __shfl_xor(sq, 4);
        sq += __shfl_xor(sq, 8);
        sq += __shfl_xor(sq, 16);
        float rstd = rsqrtf(sq * (1.f / 128.f) + 1e-5f);
        #pragma unroll
        for (int g = 0; g < 4; ++g)
            op[ro + g * 32 + lo] = (x[g] - mean) * rstd * gb[g] + bb[g];
    }
}

extern "C" void kernel_launch(void* const* d_in, const int* in_sizes, int n_in,
                              void* d_out, int out_size, void* d_ws, size_t ws_size,
                              hipStream_t stream) {
    (void)in_sizes; (void)n_in; (void)out_size; (void)ws_size;
    const float* Q    = (const float*)d_in[0];
    const float* K    = (const float*)d_in[1];
    const float* V    = (const float*)d_in[2];
    const float* QP   = (const float*)d_in[3];
    const float* KP   = (const float*)d_in[4];
    const float* WQw  = (const float*)d_in[6];
    const float* WQb  = (const float*)d_in[7];
    const float* WKw  = (const float*)d_in[8];
    const float* WKb  = (const float*)d_in[9];
    const float* WVw  = (const float*)d_in[10];
    const float* WVb  = (const float*)d_in[11];
    const float* WQPw = (const float*)d_in[12];
    const float* WQPb = (const float*)d_in[13];
    const float* WKPw = (const float*)d_in[14];
    const float* WKPb = (const float*)d_in[15];
    const float* qlw  = (const float*)d_in[18];
    const float* qlb  = (const float*)d_in[19];
    const float* vlw  = (const float*)d_in[20];
    const float* vlb  = (const float*)d_in[21];
    const float* lng  = (const float*)d_in[22];
    const float* lnb  = (const float*)d_in[23];
    char* ws = (char*)d_ws;
    float* out = (float*)d_out;

    k_prep<<<388, 256, 0, stream>>>(WQw, WKw, WVw, WQPw, WKPw, qlw, vlw, WVb, vlb, ws);
    k_proj<<<2624, 256, 0, stream>>>(Q, K, V, QP, KP, WQb, WKb, WVb, WQPb, WKPb, ws, out);
    k_attn<<<512, 256, 0, stream>>>(ws);
    k_out<<<256, 64, 0, stream>>>(Q, qlb, lng, lnb, ws, out);
}